// Round 1
// baseline (688.614 us; speedup 1.0000x reference)
//
#include <hip/hip_runtime.h>

// PointPillars pseudo-image scatter, inverted to a single-pass gather.
// v5: all 8 channel slabs fused into one kernel pass (slab loop in-kernel,
//     2-deep feat prefetch pipeline). Map read once (5.12 MB, was 41 MB);
//     wave count 8x down (map-load latency chain amortized over 8x stores).
// v4: two 4-cell groups per thread; all loads before all stores.
// v3: 8 channel slabs -> 8 data VGPRs/group.
// v2: u16 per-batch voxel map (5.12 MB, memset 0xFF sentinel); nontemporal
//     coalesced 16 B stores for the 655 MB output (written exactly once).

constexpr int BATCH = 16;
constexpr int CH    = 64;
constexpr int NYD   = 400;
constexpr int NXD   = 400;
constexpr int NYNX  = NYD * NXD;   // 160000 cells per batch
constexpr int SLABS = 8;           // 8 channels per slab
constexpr int CPS   = CH / SLABS;  // 8
constexpr int TILE  = 1024;        // cells per block (256 thr * 4 cells)

typedef float f4 __attribute__((ext_vector_type(4)));

// Phase 1: map[b*NYNX + y*NX + x] = per-batch voxel id (i - b*nv), u16.
// map pre-filled with 0xFFFF via memsetAsync(0xFF).
__global__ void scatter_map_kernel(const int4* __restrict__ idx,
                                   unsigned short* __restrict__ map, int n, int nv) {
    int i = blockIdx.x * blockDim.x + threadIdx.x;
    if (i < n) {
        int4 v = idx[i];             // fields: b, z, y, x
        map[v.x * NYNX + v.z * NXD + v.w] = (unsigned short)(i - v.x * nv);
    }
}

// Phase 2: out[b, c, y, x] = live ? feat[(b*nv+j)*CH + c] : 0
// Thread owns 4 x-adjacent cells and loops over all 8 channel slabs,
// prefetching slab s+1's feat rows while storing slab s.
__global__ __launch_bounds__(256)
void gather_kernel(const float* __restrict__ feat,
                   const unsigned short* __restrict__ map,
                   float* __restrict__ out, int nv) {
    const int b  = blockIdx.y;
    const int yx = blockIdx.x * TILE + threadIdx.x * 4;
    if (yx >= NYNX) return;   // no barriers below; early-exit is safe

    const unsigned short* mapb  = map  + (size_t)b * NYNX;
    const float*          featb = feat + ((size_t)b * nv) * CH;
    float*                outb  = out  + (size_t)b * CH * NYNX + yx;
    const f4 z4 = {0.f, 0.f, 0.f, 0.f};

    // one coalesced 8 B map load per thread, reused for all 8 slabs
    const ushort4 m = *reinterpret_cast<const ushort4*>(mapb + yx);
    const unsigned short js[4] = {m.x, m.y, m.z, m.w};

    f4 fA[4][2], fB[4][2];

    // prologue: load slab 0 into fA
    #pragma unroll
    for (int cc = 0; cc < 4; ++cc) {
        if (js[cc] != 0xFFFFu) {
            const f4* src = reinterpret_cast<const f4*>(featb + (size_t)js[cc] * CH);
            fA[cc][0] = src[0];
            fA[cc][1] = src[1];
        } else {
            fA[cc][0] = z4;
            fA[cc][1] = z4;
        }
    }

    #pragma unroll
    for (int s = 0; s < SLABS; ++s) {
        // after full unroll, (s & 1) is compile-time -> static buffer refs,
        // no scratch (rule: never runtime-index ext_vector arrays)
        f4 (*cur)[2] = (s & 1) ? fB : fA;
        f4 (*nxt)[2] = (s & 1) ? fA : fB;

        // ---- prefetch slab s+1 (issued before any stores of slab s) ----
        if (s + 1 < SLABS) {
            #pragma unroll
            for (int cc = 0; cc < 4; ++cc) {
                if (js[cc] != 0xFFFFu) {
                    const f4* src = reinterpret_cast<const f4*>(
                        featb + (size_t)js[cc] * CH + (s + 1) * CPS);
                    nxt[cc][0] = src[0];
                    nxt[cc][1] = src[1];
                } else {
                    nxt[cc][0] = z4;
                    nxt[cc][1] = z4;
                }
            }
        }

        // ---- store slab s: 8 dense nontemporal 16 B stores (1024 B/wave) ----
        float* outs = outb + (size_t)s * CPS * NYNX;
        #pragma unroll
        for (int k = 0; k < 2; ++k) {   // channels s*8+4k .. s*8+4k+3
            f4 r0 = {cur[0][k].x, cur[1][k].x, cur[2][k].x, cur[3][k].x};
            f4 r1 = {cur[0][k].y, cur[1][k].y, cur[2][k].y, cur[3][k].y};
            f4 r2 = {cur[0][k].z, cur[1][k].z, cur[2][k].z, cur[3][k].z};
            f4 r3 = {cur[0][k].w, cur[1][k].w, cur[2][k].w, cur[3][k].w};
            __builtin_nontemporal_store(r0, reinterpret_cast<f4*>(outs + (size_t)(4 * k + 0) * NYNX));
            __builtin_nontemporal_store(r1, reinterpret_cast<f4*>(outs + (size_t)(4 * k + 1) * NYNX));
            __builtin_nontemporal_store(r2, reinterpret_cast<f4*>(outs + (size_t)(4 * k + 2) * NYNX));
            __builtin_nontemporal_store(r3, reinterpret_cast<f4*>(outs + (size_t)(4 * k + 3) * NYNX));
        }
    }
}

// ---- Fallback path (only if d_ws is too small for the map) ----
__global__ void zero_kernel(float4* __restrict__ out, int n4) {
    int i = blockIdx.x * blockDim.x + threadIdx.x;
    if (i < n4) out[i] = make_float4(0.f, 0.f, 0.f, 0.f);
}

__global__ void direct_scatter_kernel(const float* __restrict__ feat,
                                      const int4* __restrict__ idx,
                                      float* __restrict__ out, int n) {
    int i = blockIdx.x * (blockDim.x / CH) + threadIdx.x / CH;
    int c = threadIdx.x % CH;
    if (i < n) {
        int4 v = idx[i];
        out[(size_t)(v.x * CH + c) * NYNX + v.z * NXD + v.w] = feat[(size_t)i * CH + c];
    }
}

extern "C" void kernel_launch(void* const* d_in, const int* in_sizes, int n_in,
                              void* d_out, int out_size, void* d_ws, size_t ws_size,
                              hipStream_t stream) {
    const float* feat = (const float*)d_in[0];
    const int4*  idx  = (const int4*)d_in[1];
    float*       out  = (float*)d_out;
    const int n  = in_sizes[1] / 4;          // number of pillars (192000)
    const int nv = n / BATCH;                // pillars per batch (12000)

    const size_t map_bytes = (size_t)BATCH * NYNX * sizeof(unsigned short);  // 5.12 MB
    if (ws_size >= map_bytes && nv < 0xFFFF) {
        unsigned short* map = (unsigned short*)d_ws;
        (void)hipMemsetAsync(map, 0xFF, map_bytes, stream);       // 0xFFFF fill
        scatter_map_kernel<<<(n + 255) / 256, 256, 0, stream>>>(idx, map, n, nv);
        dim3 grid((NYNX + TILE - 1) / TILE, BATCH, 1);            // (157, 16, 1)
        gather_kernel<<<grid, 256, 0, stream>>>(feat, map, out, nv);
    } else {
        int n4 = out_size / 4;
        zero_kernel<<<(n4 + 255) / 256, 256, 0, stream>>>((float4*)out, n4);
        direct_scatter_kernel<<<(n + 3) / 4, 256, 0, stream>>>(feat, idx, out, n);
    }
}